// Round 4
// baseline (312.960 us; speedup 1.0000x reference)
//
#include <hip/hip_runtime.h>

typedef __attribute__((ext_vector_type(4))) int  i32x4;
typedef __attribute__((ext_vector_type(16))) int i32x16;

#define IC   256
#define OCH  128
#define BSZ  16
#define IH   64
#define IW   64
#define OH2  128
#define OW2  128
#define QMAXF 127.0f

// ws float-offset layout
#define WS_WSCALE 0        // 256 per-ic weight absmax
#define WS_APART  256      // 8*256 per-(bq,ic) act absmax partials
#define WS_QS     2304     // 256: x multiplier 1/(sc*sx)
#define WS_WQS    2560     // 256: w multiplier sc/sw
#define WS_F      2816     // sx*sw
#define WS_WQ8    3072     // int8 [9][16][128][16] quantized weights (294912 B)

// ---------------- K1: per-channel absmax (partials over batch) ----------------
__global__ __launch_bounds__(256) void k_channel_scales(
        const float* __restrict__ x, const float* __restrict__ w,
        float* __restrict__ ws) {
    const int ic = blockIdx.x;
    const int bq = blockIdx.y;          // 0..7, two batches each
    const int t  = threadIdx.x;
    float amax = 0.f, wmax = 0.f;
    for (int bb = 2 * bq; bb < 2 * bq + 2; ++bb) {
        const float* xp = x + ((size_t)(bb * IC + ic)) * (IH * IW);
        for (int hw = t * 4; hw < IH * IW; hw += 1024) {
            float4 v = *(const float4*)(xp + hw);
            amax = fmaxf(amax, fmaxf(fmaxf(fabsf(v.x), fabsf(v.y)),
                                     fmaxf(fabsf(v.z), fabsf(v.w))));
        }
    }
    if (bq == 0)
        for (int j = t; j < OCH * 9; j += 256)
            wmax = fmaxf(wmax, fabsf(w[ic * (OCH * 9) + j]));
    __shared__ float r1[256], r2[256];
    r1[t] = wmax; r2[t] = amax;
    __syncthreads();
    for (int s = 128; s > 0; s >>= 1) {
        if (t < s) {
            r1[t] = fmaxf(r1[t], r1[t + s]);
            r2[t] = fmaxf(r2[t], r2[t + s]);
        }
        __syncthreads();
    }
    if (t == 0) {
        ws[WS_APART + bq * 256 + ic] = r2[0];
        if (bq == 0) ws[WS_WSCALE + ic] = r1[0];
    }
}

// ---------------- K2: scales + per-tensor quant steps ----------------
__global__ __launch_bounds__(256) void k_finalize(float* __restrict__ ws) {
    const int t = threadIdx.x;          // = ic
    float asc = 0.f;
    for (int q = 0; q < 8; ++q) asc = fmaxf(asc, ws[WS_APART + q * 256 + t]);
    const float wsc = ws[WS_WSCALE + t];
    float sc = sqrtf(asc) / sqrtf(wsc);
    if (sc == 0.f) sc = 1.f;
    float wm = wsc * sc;                // elementwise max of |w*sc| (monotone)
    float am = asc / sc;                // elementwise max of |x/sc|
    __shared__ float r1[256], r2[256];
    r1[t] = wm; r2[t] = am;
    __syncthreads();
    for (int s = 128; s > 0; s >>= 1) {
        if (t < s) {
            r1[t] = fmaxf(r1[t], r1[t + s]);
            r2[t] = fmaxf(r2[t], r2[t + s]);
        }
        __syncthreads();
    }
    float sw = r1[0] / QMAXF; if (sw == 0.f) sw = 1.f;
    float sx = r2[0] / QMAXF; if (sx == 0.f) sx = 1.f;
    ws[WS_QS  + t] = 1.f / (sc * sx);
    ws[WS_WQS + t] = sc / sw;
    if (t == 0) ws[WS_F] = sx * sw;
}

// ---------------- K3: quantize weights -> int8 [tap][kq(16)][oc(128)][16B] ----------------
__global__ __launch_bounds__(256) void k_quant_w(
        const float* __restrict__ w, float* __restrict__ ws) {
    const int idx = blockIdx.x * 256 + threadIdx.x;   // [tap][kq][oc][e4]
    const int e0  = (idx & 3) * 4;
    const int oc  = (idx >> 2) & 127;
    const int kq  = (idx >> 9) & 15;
    const int tap = idx >> 13;
    unsigned pack = 0;
    #pragma unroll
    for (int c = 0; c < 4; ++c) {
        const int ic = kq * 16 + e0 + c;
        float q = rintf(w[((size_t)ic * OCH + oc) * 9 + tap] * ws[WS_WQS + ic]);
        q = fminf(fmaxf(q, -128.f), 127.f);
        pack |= ((unsigned)((int)q & 255)) << (8 * c);
    }
    ((unsigned*)(ws + WS_WQ8))[idx] = pack;
}

// ---------------- K4: MFMA implicit-GEMM conv, K-folded taps ----------------
// A-tile int8 [r(2)][v(65)][ic(256)], byte = (r*65+v)*256 + (ic ^ ((v&15)<<4))
__device__ __forceinline__ i32x4 load_a(const char* qa, int R, int S, int ks, int m, int lane) {
    const int v = m * 32 + (lane & 31) + S;
    const unsigned byte = (unsigned)((R * 65 + v) * 256)
        + (((unsigned)(ks * 32 + ((lane >> 5) << 4))) ^ (((unsigned)(v & 15)) << 4));
    return *(const i32x4*)(qa + byte);
}

__device__ __forceinline__ i32x4 load_b(const char* wq8, int tap, int ks, int oc, int lane) {
    const size_t off = ((size_t)((tap * 16 + ks * 2 + (lane >> 5)) * OCH + oc)) * 16;
    return *(const i32x4*)(wq8 + off);
}

template<int NN, int NT>
__device__ __forceinline__ void gemm_run(const char* qa, const char* wq8,
        const int (&taps)[NT], int ocb, int lane, i32x16 (&acc)[2][4]) {
    const int oc0 = ocb + (lane & 31);
    #pragma unroll
    for (int t = 0; t < NT; ++t) {
        const int tap = taps[t];
        const int R = tap < 3 ? 1 : 0;
        const int S = (tap % 3 == 0) ? 1 : 0;
        #pragma unroll
        for (int ks = 0; ks < 8; ++ks) {
            const i32x4 a0 = load_a(qa, R, S, ks, 0, lane);
            const i32x4 a1 = load_a(qa, R, S, ks, 1, lane);
            #pragma unroll
            for (int n = 0; n < NN; ++n) {
                const i32x4 bb = load_b(wq8, tap, ks, oc0 + n * 32, lane);
                acc[0][n] = __builtin_amdgcn_mfma_i32_32x32x32_i8(a0, bb, acc[0][n], 0, 0, 0);
                acc[1][n] = __builtin_amdgcn_mfma_i32_32x32x32_i8(a1, bb, acc[1][n], 0, 0, 0);
            }
        }
    }
}

__global__ __launch_bounds__(576, 6) void k_conv(
        const float* __restrict__ x, const float* __restrict__ bias,
        const float* __restrict__ ws, float* __restrict__ out) {
    // LDS: A-tile 33280 B, later overlaid by C-buffer [64][130] ints (33280 B)
    __shared__ __align__(16) char smem[33280 + 1024 + 512];
    char*  qa    = smem;
    int*   cbuf  = (int*)smem;
    float* sqs   = (float*)(smem + 33280);
    float* sbias = (float*)(smem + 33280 + 1024);

    const int tid  = threadIdx.x;
    const int u    = blockIdx.x;     // output rows 2u, 2u+1
    const int b    = blockIdx.y;
    const int lane = tid & 63;
    const int wid  = tid >> 6;       // 0..8

    if (tid < 256) sqs[tid] = ws[WS_QS + tid];
    else if (tid >= 256 && tid < 384) sbias[tid - 256] = bias[tid - 256];
    else if (tid >= 448) {           // zero pad column v=64 (both r)
        const int t2 = tid - 448;    // 0..127
        ((int*)(qa + ((t2 >> 6) * 65 + 64) * 256))[t2 & 63] = 0;
    }
    __syncthreads();

    // stage + quantize x rows u, u+1 -> int8 LDS (coalesced: lane <-> col)
    for (int j = tid; j < 8192; j += 576) {
        const int v   = j & 63;
        const int icq = (j >> 6) & 63;
        const int r   = j >> 12;
        const int row = u + r;
        const int ic0 = icq * 4;
        unsigned pack = 0;
        if (row < IH) {
            const float* xp = x + (((size_t)(b * IC + ic0)) * IH + row) * IW + v;
            #pragma unroll
            for (int c = 0; c < 4; ++c) {
                float q = fminf(fmaxf(rintf(xp[(size_t)c * IH * IW] * sqs[ic0 + c]),
                                      -128.f), 127.f);
                pack |= ((unsigned)((int)q & 255)) << (8 * c);
            }
        }
        *(unsigned*)(qa + (r * 65 + v) * 256 + ((unsigned)ic0 ^ (((unsigned)(v & 15)) << 4))) = pack;
    }
    __syncthreads();

    const char* wq8 = (const char*)(ws + WS_WQ8);

    i32x16 acc[2][4];
    #pragma unroll
    for (int m = 0; m < 2; ++m)
        #pragma unroll
        for (int n = 0; n < 4; ++n) acc[m][n] = (i32x16)(0);

    // 9 balanced waves, 64 MFMA each; taps folded into K; each output owned by ONE wave.
    int row_, par_, ocb_, nn_;
    if (wid == 0) {
        row_ = 0; par_ = 0; ocb_ = 0; nn_ = 4;
        const int taps[1] = {4};
        gemm_run<4, 1>(qa, wq8, taps, ocb_, lane, acc);
    } else if (wid <= 2) {
        row_ = 0; par_ = 1; ocb_ = (wid - 1) * 64; nn_ = 2;
        const int taps[2] = {3, 5};
        gemm_run<2, 2>(qa, wq8, taps, ocb_, lane, acc);
    } else if (wid <= 4) {
        row_ = 1; par_ = 0; ocb_ = (wid - 3) * 64; nn_ = 2;
        const int taps[2] = {1, 7};
        gemm_run<2, 2>(qa, wq8, taps, ocb_, lane, acc);
    } else {
        row_ = 1; par_ = 1; ocb_ = (wid - 5) * 32; nn_ = 1;
        const int taps[4] = {0, 2, 6, 8};
        gemm_run<1, 4>(qa, wq8, taps, ocb_, lane, acc);
    }

    // epilogue: 4 phases (row, oc-half); C-buffer overlays dead A-tile
    const float f = ws[WS_F];
    __syncthreads();                 // all waves past last A-read
    #pragma unroll
    for (int ph = 0; ph < 4; ++ph) {
        if (ph) __syncthreads();     // previous store phase done reading cbuf
        const int pb = (ph & 1) * 64;
        if (row_ == (ph >> 1)) {
            #pragma unroll
            for (int n = 0; n < 4; ++n) {
                if (n < nn_) {
                    const int ocg = ocb_ + n * 32 + (lane & 31);
                    if (ocg >= pb && ocg < pb + 64) {
                        const int vb = 4 * (lane >> 5);
                        #pragma unroll
                        for (int m = 0; m < 2; ++m)
                            #pragma unroll
                            for (int reg = 0; reg < 16; ++reg) {
                                const int v = m * 32 + (reg & 3) + 8 * (reg >> 2) + vb;
                                cbuf[(ocg - pb) * 130 + 2 * v + par_] = acc[m][n][reg];
                            }
                    }
                }
            }
        }
        __syncthreads();
        const int oh = 2 * u + (ph >> 1);
        for (int i = tid; i < 8192; i += 576) {
            const int ocl = i >> 7, ow = i & 127;
            const int oc = pb + ocl;
            out[(((size_t)(b * OCH + oc)) * OH2 + oh) * OW2 + ow] =
                fmaf((float)cbuf[ocl * 130 + ow], f, sbias[oc]);
        }
    }
}

extern "C" void kernel_launch(void* const* d_in, const int* in_sizes, int n_in,
                              void* d_out, int out_size, void* d_ws, size_t ws_size,
                              hipStream_t stream) {
    const float* x    = (const float*)d_in[0];
    const float* w    = (const float*)d_in[1];
    const float* bias = (const float*)d_in[2];
    float* ws  = (float*)d_ws;
    float* out = (float*)d_out;

    k_channel_scales<<<dim3(256, 8), 256, 0, stream>>>(x, w, ws);
    k_finalize<<<1, 256, 0, stream>>>(ws);
    k_quant_w<<<288, 256, 0, stream>>>(w, ws);
    k_conv<<<dim3(IH, BSZ), 576, 0, stream>>>(x, bias, ws, out);
}

// Round 5
// 104.186 us; speedup vs baseline: 3.0039x; 3.0039x over previous
//
#include <hip/hip_runtime.h>

typedef __attribute__((ext_vector_type(4))) int  i32x4;
typedef __attribute__((ext_vector_type(16))) int i32x16;

#define IC   256
#define OCH  128
#define BSZ  16
#define IH   64
#define IW   64
#define OH2  128
#define OW2  128
#define QMAXF 127.0f

// ws float-offset layout
#define WS_WSCALE 0        // 256 per-ic weight absmax
#define WS_APART  256      // 8*256 per-(bq,ic) act absmax partials
#define WS_QS     2304     // 256: x multiplier 1/(sc*sx)
#define WS_WQS    2560     // 256: w multiplier sc/sw
#define WS_F      2816     // sx*sw
#define WS_WQ8    3072     // int8 [9][16][128][16] quantized weights (294912 B)

// ---------------- K1: per-channel absmax (partials over batch) ----------------
__global__ __launch_bounds__(256) void k_channel_scales(
        const float* __restrict__ x, const float* __restrict__ w,
        float* __restrict__ ws) {
    const int ic = blockIdx.x;
    const int bq = blockIdx.y;          // 0..7, two batches each
    const int t  = threadIdx.x;
    float amax = 0.f, wmax = 0.f;
    for (int bb = 2 * bq; bb < 2 * bq + 2; ++bb) {
        const float* xp = x + ((size_t)(bb * IC + ic)) * (IH * IW);
        for (int hw = t * 4; hw < IH * IW; hw += 1024) {
            float4 v = *(const float4*)(xp + hw);
            amax = fmaxf(amax, fmaxf(fmaxf(fabsf(v.x), fabsf(v.y)),
                                     fmaxf(fabsf(v.z), fabsf(v.w))));
        }
    }
    if (bq == 0)
        for (int j = t; j < OCH * 9; j += 256)
            wmax = fmaxf(wmax, fabsf(w[ic * (OCH * 9) + j]));
    __shared__ float r1[256], r2[256];
    r1[t] = wmax; r2[t] = amax;
    __syncthreads();
    for (int s = 128; s > 0; s >>= 1) {
        if (t < s) {
            r1[t] = fmaxf(r1[t], r1[t + s]);
            r2[t] = fmaxf(r2[t], r2[t + s]);
        }
        __syncthreads();
    }
    if (t == 0) {
        ws[WS_APART + bq * 256 + ic] = r2[0];
        if (bq == 0) ws[WS_WSCALE + ic] = r1[0];
    }
}

// ---------------- K2: scales + per-tensor quant steps ----------------
__global__ __launch_bounds__(256) void k_finalize(float* __restrict__ ws) {
    const int t = threadIdx.x;          // = ic
    float asc = 0.f;
    for (int q = 0; q < 8; ++q) asc = fmaxf(asc, ws[WS_APART + q * 256 + t]);
    const float wsc = ws[WS_WSCALE + t];
    float sc = sqrtf(asc) / sqrtf(wsc);
    if (sc == 0.f) sc = 1.f;
    float wm = wsc * sc;                // elementwise max of |w*sc| (monotone)
    float am = asc / sc;                // elementwise max of |x/sc|
    __shared__ float r1[256], r2[256];
    r1[t] = wm; r2[t] = am;
    __syncthreads();
    for (int s = 128; s > 0; s >>= 1) {
        if (t < s) {
            r1[t] = fmaxf(r1[t], r1[t + s]);
            r2[t] = fmaxf(r2[t], r2[t + s]);
        }
        __syncthreads();
    }
    float sw = r1[0] / QMAXF; if (sw == 0.f) sw = 1.f;
    float sx = r2[0] / QMAXF; if (sx == 0.f) sx = 1.f;
    ws[WS_QS  + t] = 1.f / (sc * sx);
    ws[WS_WQS + t] = sc / sw;
    if (t == 0) ws[WS_F] = sx * sw;
}

// ---------------- K3: quantize weights -> int8 [tap][kq(16)][oc(128)][16B] ----------------
__global__ __launch_bounds__(256) void k_quant_w(
        const float* __restrict__ w, float* __restrict__ ws) {
    const int idx = blockIdx.x * 256 + threadIdx.x;   // [tap][kq][oc][e4]
    const int e0  = (idx & 3) * 4;
    const int oc  = (idx >> 2) & 127;
    const int kq  = (idx >> 9) & 15;
    const int tap = idx >> 13;
    unsigned pack = 0;
    #pragma unroll
    for (int c = 0; c < 4; ++c) {
        const int ic = kq * 16 + e0 + c;
        float q = rintf(w[((size_t)ic * OCH + oc) * 9 + tap] * ws[WS_WQS + ic]);
        q = fminf(fmaxf(q, -128.f), 127.f);
        pack |= ((unsigned)((int)q & 255)) << (8 * c);
    }
    ((unsigned*)(ws + WS_WQ8))[idx] = pack;
}

// ---------------- K4: MFMA implicit-GEMM conv, K-folded taps ----------------
// A-tile int8 [r(2)][v(65)][ic(256)], byte = (r*65+v)*256 + (ic ^ ((v&15)<<4))
__device__ __forceinline__ i32x4 load_a(const char* qa, int R, int S, int ks, int m, int lane) {
    const int v = m * 32 + (lane & 31) + S;
    const unsigned byte = (unsigned)((R * 65 + v) * 256)
        + (((unsigned)(ks * 32 + ((lane >> 5) << 4))) ^ (((unsigned)(v & 15)) << 4));
    return *(const i32x4*)(qa + byte);
}

__device__ __forceinline__ i32x4 load_b(const char* wq8, int tap, int ks, int oc, int lane) {
    const size_t off = ((size_t)((tap * 16 + ks * 2 + (lane >> 5)) * OCH + oc)) * 16;
    return *(const i32x4*)(wq8 + off);
}

template<int NN, int NT>
__device__ __forceinline__ void gemm_run(const char* qa, const char* wq8,
        const int (&taps)[NT], int ocb, int lane, i32x16 (&acc)[2][2]) {
    const int oc0 = ocb + (lane & 31);
    #pragma unroll
    for (int t = 0; t < NT; ++t) {
        const int tap = taps[t];
        const int R = tap < 3 ? 1 : 0;
        const int S = (tap % 3 == 0) ? 1 : 0;
        #pragma unroll
        for (int ks = 0; ks < 8; ++ks) {
            const i32x4 a0 = load_a(qa, R, S, ks, 0, lane);
            const i32x4 a1 = load_a(qa, R, S, ks, 1, lane);
            #pragma unroll
            for (int n = 0; n < NN; ++n) {
                const i32x4 bb = load_b(wq8, tap, ks, oc0 + n * 32, lane);
                acc[0][n] = __builtin_amdgcn_mfma_i32_32x32x32_i8(a0, bb, acc[0][n], 0, 0, 0);
                acc[1][n] = __builtin_amdgcn_mfma_i32_32x32x32_i8(a1, bb, acc[1][n], 0, 0, 0);
            }
        }
    }
}

__global__ __launch_bounds__(640) void k_conv(
        const float* __restrict__ x, const float* __restrict__ bias,
        const float* __restrict__ ws, float* __restrict__ out) {
    // LDS: A-tile 33280 B, later overlaid by per-phase C-buffer [64][130] ints (33280 B)
    __shared__ __align__(16) char smem[33280 + 1024 + 512];
    char*  qa    = smem;
    int*   cbuf  = (int*)smem;
    float* sqs   = (float*)(smem + 33280);
    float* sbias = (float*)(smem + 33280 + 1024);

    const int tid  = threadIdx.x;
    const int u    = blockIdx.x;     // output rows 2u, 2u+1
    const int b    = blockIdx.y;
    const int lane = tid & 63;
    const int wid  = tid >> 6;       // 0..9

    if (tid < 256) sqs[tid] = ws[WS_QS + tid];
    else if (tid < 384) sbias[tid - 256] = bias[tid - 256];
    else if (tid >= 512) {           // zero pad column v=64 (both r)
        const int t2 = tid - 512;    // 0..127
        ((int*)(qa + ((t2 >> 6) * 65 + 64) * 256))[t2 & 63] = 0;
    }
    __syncthreads();

    // stage + quantize x rows u, u+1 -> int8 LDS (coalesced: lane <-> col)
    for (int j = tid; j < 8192; j += 640) {
        const int v   = j & 63;
        const int icq = (j >> 6) & 63;
        const int r   = j >> 12;
        const int row = u + r;
        const int ic0 = icq * 4;
        unsigned pack = 0;
        if (row < IH) {
            const float* xp = x + (((size_t)(b * IC + ic0)) * IH + row) * IW + v;
            #pragma unroll
            for (int c = 0; c < 4; ++c) {
                float q = fminf(fmaxf(rintf(xp[(size_t)c * IH * IW] * sqs[ic0 + c]),
                                      -128.f), 127.f);
                pack |= ((unsigned)((int)q & 255)) << (8 * c);
            }
        }
        *(unsigned*)(qa + (r * 65 + v) * 256 + ((unsigned)ic0 ^ (((unsigned)(v & 15)) << 4))) = pack;
    }
    __syncthreads();

    const char* wq8 = (const char*)(ws + WS_WQ8);

    // uniform 64-reg accumulator (proven spill-free shape from round 2)
    i32x16 acc[2][2];
    acc[0][0] = (i32x16)(0); acc[0][1] = (i32x16)(0);
    acc[1][0] = (i32x16)(0); acc[1][1] = (i32x16)(0);

    // 10 waves; taps folded into K; each output owned by ONE wave.
    // class A (row0,par0, tap 4, K=256)  -> wid 0,1 (N=64 each, 32 MFMA)
    // class B (row0,par1, taps 3,5)      -> wid 2,3 (N=64, 64 MFMA)
    // class C (row1,par0, taps 1,7)      -> wid 4,5 (N=64, 64 MFMA)
    // class D (row1,par1, taps 0,2,6,8)  -> wid 6..9 (N=32, 64 MFMA)
    int row_, par_, ocb_, nn_;
    if (wid < 2) {
        row_ = 0; par_ = 0; ocb_ = wid * 64; nn_ = 2;
        const int taps[1] = {4};
        gemm_run<2, 1>(qa, wq8, taps, ocb_, lane, acc);
    } else if (wid < 4) {
        row_ = 0; par_ = 1; ocb_ = (wid - 2) * 64; nn_ = 2;
        const int taps[2] = {3, 5};
        gemm_run<2, 2>(qa, wq8, taps, ocb_, lane, acc);
    } else if (wid < 6) {
        row_ = 1; par_ = 0; ocb_ = (wid - 4) * 64; nn_ = 2;
        const int taps[2] = {1, 7};
        gemm_run<2, 2>(qa, wq8, taps, ocb_, lane, acc);
    } else {
        row_ = 1; par_ = 1; ocb_ = (wid - 6) * 32; nn_ = 1;
        const int taps[4] = {0, 2, 6, 8};
        gemm_run<1, 4>(qa, wq8, taps, ocb_, lane, acc);
    }

    // epilogue: 4 phases (row, oc-half); C-buffer overlays dead A-tile
    const float f = ws[WS_F];
    __syncthreads();                 // all waves past last A-read
    #pragma unroll
    for (int ph = 0; ph < 4; ++ph) {
        if (ph) __syncthreads();     // previous store phase done reading cbuf
        const int pb = (ph & 1) * 64;
        if (row_ == (ph >> 1)) {
            #pragma unroll
            for (int n = 0; n < 2; ++n) {
                if (n < nn_) {
                    const int ocg = ocb_ + n * 32 + (lane & 31);
                    if ((ocg & 64) == pb) {
                        const int vb = 4 * (lane >> 5);
                        #pragma unroll
                        for (int m = 0; m < 2; ++m)
                            #pragma unroll
                            for (int reg = 0; reg < 16; ++reg) {
                                const int v = m * 32 + (reg & 3) + 8 * (reg >> 2) + vb;
                                cbuf[(ocg & 63) * 130 + 2 * v + par_] = acc[m][n][reg];
                            }
                    }
                }
            }
        }
        __syncthreads();
        const int oh = 2 * u + (ph >> 1);
        for (int i = tid; i < 8192; i += 640) {
            const int ocl = i >> 7, ow = i & 127;
            const int oc = pb + ocl;
            out[(((size_t)(b * OCH + oc)) * OH2 + oh) * OW2 + ow] =
                fmaf((float)cbuf[ocl * 130 + ow], f, sbias[oc]);
        }
    }
}

extern "C" void kernel_launch(void* const* d_in, const int* in_sizes, int n_in,
                              void* d_out, int out_size, void* d_ws, size_t ws_size,
                              hipStream_t stream) {
    const float* x    = (const float*)d_in[0];
    const float* w    = (const float*)d_in[1];
    const float* bias = (const float*)d_in[2];
    float* ws  = (float*)d_ws;
    float* out = (float*)d_out;

    k_channel_scales<<<dim3(256, 8), 256, 0, stream>>>(x, w, ws);
    k_finalize<<<1, 256, 0, stream>>>(ws);
    k_quant_w<<<288, 256, 0, stream>>>(w, ws);
    k_conv<<<dim3(IH, BSZ), 640, 0, stream>>>(x, bias, ws, out);
}

// Round 6
// 81.288 us; speedup vs baseline: 3.8500x; 1.2817x over previous
//
#include <hip/hip_runtime.h>

typedef __attribute__((ext_vector_type(4))) int  i32x4;
typedef __attribute__((ext_vector_type(16))) int i32x16;

#define IC   256
#define OCH  128
#define BSZ  16
#define IH   64
#define IW   64
#define OH2  128
#define OW2  128
#define QMAXF 127.0f

// ws float-offset layout
#define WS_WSCALE 0        // 256 per-ic weight absmax
#define WS_APART  256      // 8*256 per-(bq,ic) act absmax partials
#define WS_QS     2304     // 256: x multiplier 1/(sc*sx)
#define WS_WQS    2560     // 256: w multiplier sc/sw
#define WS_F      2816     // sx*sw
#define WS_WQ8    3072     // int8 [9][16][128][16] quantized weights (294912 B)

// ---------------- K1: per-channel absmax (partials over batch) ----------------
__global__ __launch_bounds__(256) void k_channel_scales(
        const float* __restrict__ x, const float* __restrict__ w,
        float* __restrict__ ws) {
    const int ic = blockIdx.x;
    const int bq = blockIdx.y;          // 0..7, two batches each
    const int t  = threadIdx.x;
    float amax = 0.f, wmax = 0.f;
    for (int bb = 2 * bq; bb < 2 * bq + 2; ++bb) {
        const float* xp = x + ((size_t)(bb * IC + ic)) * (IH * IW);
        for (int hw = t * 4; hw < IH * IW; hw += 1024) {
            float4 v = *(const float4*)(xp + hw);
            amax = fmaxf(amax, fmaxf(fmaxf(fabsf(v.x), fabsf(v.y)),
                                     fmaxf(fabsf(v.z), fabsf(v.w))));
        }
    }
    if (bq == 0)
        for (int j = t; j < OCH * 9; j += 256)
            wmax = fmaxf(wmax, fabsf(w[ic * (OCH * 9) + j]));
    __shared__ float r1[256], r2[256];
    r1[t] = wmax; r2[t] = amax;
    __syncthreads();
    for (int s = 128; s > 0; s >>= 1) {
        if (t < s) {
            r1[t] = fmaxf(r1[t], r1[t + s]);
            r2[t] = fmaxf(r2[t], r2[t + s]);
        }
        __syncthreads();
    }
    if (t == 0) {
        ws[WS_APART + bq * 256 + ic] = r2[0];
        if (bq == 0) ws[WS_WSCALE + ic] = r1[0];
    }
}

// ---------------- K2: scales + per-tensor quant steps ----------------
__global__ __launch_bounds__(256) void k_finalize(float* __restrict__ ws) {
    const int t = threadIdx.x;          // = ic
    float asc = 0.f;
    for (int q = 0; q < 8; ++q) asc = fmaxf(asc, ws[WS_APART + q * 256 + t]);
    const float wsc = ws[WS_WSCALE + t];
    float sc = sqrtf(asc) / sqrtf(wsc);
    if (sc == 0.f) sc = 1.f;
    float wm = wsc * sc;                // elementwise max of |w*sc| (monotone)
    float am = asc / sc;                // elementwise max of |x/sc|
    __shared__ float r1[256], r2[256];
    r1[t] = wm; r2[t] = am;
    __syncthreads();
    for (int s = 128; s > 0; s >>= 1) {
        if (t < s) {
            r1[t] = fmaxf(r1[t], r1[t + s]);
            r2[t] = fmaxf(r2[t], r2[t + s]);
        }
        __syncthreads();
    }
    float sw = r1[0] / QMAXF; if (sw == 0.f) sw = 1.f;
    float sx = r2[0] / QMAXF; if (sx == 0.f) sx = 1.f;
    ws[WS_QS  + t] = 1.f / (sc * sx);
    ws[WS_WQS + t] = sc / sw;
    if (t == 0) ws[WS_F] = sx * sw;
}

// ---------------- K3: quantize weights -> int8 [tap][kq(16)][oc(128)][16B] ----------------
__global__ __launch_bounds__(256) void k_quant_w(
        const float* __restrict__ w, float* __restrict__ ws) {
    const int idx = blockIdx.x * 256 + threadIdx.x;   // [tap][kq][oc][e4]
    const int e0  = (idx & 3) * 4;
    const int oc  = (idx >> 2) & 127;
    const int kq  = (idx >> 9) & 15;
    const int tap = idx >> 13;
    unsigned pack = 0;
    #pragma unroll
    for (int c = 0; c < 4; ++c) {
        const int ic = kq * 16 + e0 + c;
        float q = rintf(w[((size_t)ic * OCH + oc) * 9 + tap] * ws[WS_WQS + ic]);
        q = fminf(fmaxf(q, -128.f), 127.f);
        pack |= ((unsigned)((int)q & 255)) << (8 * c);
    }
    ((unsigned*)(ws + WS_WQ8))[idx] = pack;
}

// ---------------- K4: MFMA implicit-GEMM conv, K-folded taps, 8 waves ----------------
// A-tile int8 [r(2)][v(66)][ic(256)], byte = (r*66+v)*256 + (ic ^ ((v&15)<<4))
__device__ __forceinline__ i32x4 load_a(const char* qa, int R, int S, int ks, int m, int lane) {
    const int v = m * 32 + (lane & 31) + S;
    const unsigned byte = (unsigned)((R * 66 + v) * 256)
        + (((unsigned)(ks * 32 + ((lane >> 5) << 4))) ^ (((unsigned)(v & 15)) << 4));
    return *(const i32x4*)(qa + byte);
}

__device__ __forceinline__ i32x4 load_b(const char* wq8, int tap, int ks, int oc, int lane) {
    const size_t off = ((size_t)((tap * 16 + ks * 2 + (lane >> 5)) * OCH + oc)) * 16;
    return *(const i32x4*)(wq8 + off);
}

template<int NT>
__device__ __forceinline__ void gemm_run(const char* qa, const char* wq8,
        const int (&taps)[NT], int oc0, int lane, i32x16 (&acc)[2]) {
    #pragma unroll
    for (int t = 0; t < NT; ++t) {
        const int tap = taps[t];
        const int R = tap < 3 ? 1 : 0;
        const int S = (tap % 3 == 0) ? 1 : 0;
        #pragma unroll
        for (int ks = 0; ks < 8; ++ks) {
            const i32x4 a0 = load_a(qa, R, S, ks, 0, lane);
            const i32x4 a1 = load_a(qa, R, S, ks, 1, lane);
            const i32x4 bb = load_b(wq8, tap, ks, oc0, lane);
            acc[0] = __builtin_amdgcn_mfma_i32_32x32x32_i8(a0, bb, acc[0], 0, 0, 0);
            acc[1] = __builtin_amdgcn_mfma_i32_32x32x32_i8(a1, bb, acc[1], 0, 0, 0);
        }
    }
}

__global__ __launch_bounds__(512) void k_conv(
        const float* __restrict__ x, const float* __restrict__ bias,
        const float* __restrict__ ws, float* __restrict__ out) {
    // LDS: A-tile 33792 B, overlaid in epilogue by C-buffer [64][130] ints (33280 B)
    __shared__ __align__(16) char smem[33792];
    char* qa   = smem;
    int*  cbuf = (int*)smem;

    const int tid  = threadIdx.x;
    const int u    = blockIdx.x;     // output rows 2u, 2u+1
    const int b    = blockIdx.y;
    const int lane = tid & 63;
    const int wid  = tid >> 6;       // 0..7
    const int q    = wid >> 1;       // oc quarter (32 wide)
    const int pa   = wid & 1;        // pairing

    // zero pad column v=64 (both r); disjoint from staging writes, covered by barrier
    if (tid < 128)
        ((int*)(qa + ((tid >> 6) * 66 + 64) * 256))[tid & 63] = 0;

    // stage + quantize x rows u, u+1 -> int8 LDS (lane <-> col, coalesced);
    // per-iteration scale factors are wave-uniform -> s_loads from L2
    for (int j = tid; j < 8192; j += 512) {
        const int v   = j & 63;
        const int icq = (j >> 6) & 63;
        const int r   = j >> 12;
        const int row = u + r;
        const int ic0 = icq * 4;
        unsigned pack = 0;
        if (row < IH) {
            const float* xp = x + (((size_t)(b * IC + ic0)) * IH + row) * IW + v;
            #pragma unroll
            for (int c = 0; c < 4; ++c) {
                float qv = fminf(fmaxf(rintf(xp[(size_t)c * IH * IW] * ws[WS_QS + ic0 + c]),
                                       -128.f), 127.f);
                pack |= ((unsigned)((int)qv & 255)) << (8 * c);
            }
        }
        *(unsigned*)(qa + (r * 66 + v) * 256 + ((unsigned)ic0 ^ (((unsigned)(v & 15)) << 4))) = pack;
    }
    __syncthreads();

    const char* wq8 = (const char*)(ws + WS_WQ8);
    const int oc0 = q * 32 + (lane & 31);

    // two static accumulator slots per wave (64 regs total, proven spill-free)
    i32x16 accA[2], accB[2];         // A: row0 slot, B: row1 slot
    accA[0] = (i32x16)(0); accA[1] = (i32x16)(0);
    accB[0] = (i32x16)(0); accB[1] = (i32x16)(0);

    // pairing 0: (row0,par0) tap{4}  + (row1,par1) taps{0,2,6,8}   (80 MFMA)
    // pairing 1: (row0,par1) taps{3,5} + (row1,par0) taps{1,7}     (64 MFMA)
    if (pa == 0) {
        const int t0[1] = {4};
        gemm_run<1>(qa, wq8, t0, oc0, lane, accA);
        const int t1[4] = {0, 2, 6, 8};
        gemm_run<4>(qa, wq8, t1, oc0, lane, accB);
    } else {
        const int t0[2] = {3, 5};
        gemm_run<2>(qa, wq8, t0, oc0, lane, accA);
        const int t1[2] = {1, 7};
        gemm_run<2>(qa, wq8, t1, oc0, lane, accB);
    }

    // epilogue: 4 phases (row r, oc-half h); C-buffer overlays dead A-tile
    const float f = ws[WS_F];
    __syncthreads();                 // all waves past last A-read
    #pragma unroll
    for (int ph = 0; ph < 4; ++ph) {
        const int r = ph >> 1, h = ph & 1;
        if (ph) __syncthreads();     // previous store phase done reading cbuf
        if ((q >> 1) == h) {
            const int par = pa ^ r;
            const int ocl = (q & 1) * 32 + (lane & 31);
            const int vb  = 4 * (lane >> 5);
            #pragma unroll
            for (int m = 0; m < 2; ++m)
                #pragma unroll
                for (int reg = 0; reg < 16; ++reg) {
                    const int v = m * 32 + (reg & 3) + 8 * (reg >> 2) + vb;
                    cbuf[ocl * 130 + 2 * v + par] = (r == 0) ? accA[m][reg] : accB[m][reg];
                }
        }
        __syncthreads();
        const int oh = 2 * u + r;
        for (int i = tid; i < 8192; i += 512) {
            const int ocl = i >> 7, ow = i & 127;
            const int oc = h * 64 + ocl;        // wave-uniform -> bias via s_load
            out[(((size_t)(b * OCH + oc)) * OH2 + oh) * OW2 + ow] =
                fmaf((float)cbuf[ocl * 130 + ow], f, bias[oc]);
        }
    }
}

extern "C" void kernel_launch(void* const* d_in, const int* in_sizes, int n_in,
                              void* d_out, int out_size, void* d_ws, size_t ws_size,
                              hipStream_t stream) {
    const float* x    = (const float*)d_in[0];
    const float* w    = (const float*)d_in[1];
    const float* bias = (const float*)d_in[2];
    float* ws  = (float*)d_ws;
    float* out = (float*)d_out;

    k_channel_scales<<<dim3(256, 8), 256, 0, stream>>>(x, w, ws);
    k_finalize<<<1, 256, 0, stream>>>(ws);
    k_quant_w<<<288, 256, 0, stream>>>(w, ws);
    k_conv<<<dim3(IH, BSZ), 512, 0, stream>>>(x, bias, ws, out);
}